// Round 5
// baseline (521.529 us; speedup 1.0000x reference)
//
#include <hip/hip_runtime.h>

#define NN 50000
#define EE 800000
#define DD 16
#define DD2 256
#define ETOT (EE + NN)
#define NB 196  // ceil(50000/256)

typedef __bf16 bf16x8 __attribute__((ext_vector_type(8)));
typedef float f32x4 __attribute__((ext_vector_type(4)));
typedef float f32x2 __attribute__((ext_vector_type(2)));

__device__ inline unsigned short f2bf(float f) {
    unsigned int u = __float_as_uint(f);
    return (unsigned short)((u + 0x7FFFu + ((u >> 16) & 1u)) >> 16);
}

__device__ inline void gl2lds16(const void* g, void* l) {
    __builtin_amdgcn_global_load_lds((const __attribute__((address_space(1))) unsigned int*)g,
                                     (__attribute__((address_space(3))) unsigned int*)l, 16, 0, 0);
}

// ---------------- CSR build ----------------
__global__ void k_count(const int* ei, int* counts) {
    int e = blockIdx.x * 256 + threadIdx.x;
    if (e < EE) atomicAdd(&counts[ei[EE + e]], 1);
}

__global__ void k_scan1(const int* counts, int* partial, int* bsum) {
    __shared__ int sh[256];
    int t = threadIdx.x;
    int n = blockIdx.x * 256 + t;
    int v = (n < NN) ? counts[n] + 1 : 0;  // +1 self-loop
    sh[t] = v;
    __syncthreads();
    for (int d = 1; d < 256; d <<= 1) {
        int x = (t >= d) ? sh[t - d] : 0;
        __syncthreads();
        sh[t] += x;
        __syncthreads();
    }
    if (n < NN) partial[n] = sh[t];
    if (t == 255) bsum[blockIdx.x] = sh[255];
}

__global__ void k_scan2(const int* bsum, int* boff) {  // 1 block
    __shared__ int sh[256];
    int t = threadIdx.x;
    int v = (t < NB) ? bsum[t] : 0;
    sh[t] = v;
    __syncthreads();
    for (int d = 1; d < 256; d <<= 1) {
        int x = (t >= d) ? sh[t - d] : 0;
        __syncthreads();
        sh[t] += x;
        __syncthreads();
    }
    if (t < NB) boff[t] = sh[t] - v;  // exclusive
}

__global__ void k_scan3(const int* counts, const int* partial, const int* boff,
                        int* row_start, int* cursor) {
    int n = blockIdx.x * 256 + threadIdx.x;
    if (n < NN) {
        int rs = partial[n] - (counts[n] + 1) + boff[blockIdx.x];
        row_start[n] = rs;
        cursor[n] = rs;
        if (n == NN - 1) row_start[NN] = partial[n] + boff[blockIdx.x];
    }
}

// scatter + fused per-edge exp coefficients (written in CSR position)
__global__ void k_scatter(const int* ei, int* cursor, const float* asrc, const float* adst,
                          int* srt, float* exarr) {
    int i = blockIdx.x * 256 + threadIdx.x;
    if (i >= ETOT) return;
    int s, d;
    if (i < EE) { s = ei[i]; d = ei[EE + i]; }
    else { s = d = i - EE; }
    int pos = atomicAdd(&cursor[d], 1);
    srt[pos] = s;
    const float4* pa = (const float4*)(asrc + (size_t)s * 8);
    const float4* pd = (const float4*)(adst + (size_t)d * 8);
    float4 a0 = pa[0], a1 = pa[1], d0 = pd[0], d1 = pd[1];
    float av[8] = {a0.x, a0.y, a0.z, a0.w, a1.x, a1.y, a1.z, a1.w};
    float dv[8] = {d0.x, d0.y, d0.z, d0.w, d1.x, d1.y, d1.z, d1.w};
    float ex[8];
#pragma unroll
    for (int c = 0; c < 8; ++c) {
        float al = av[c] + dv[c];
        al = (al >= 0.f) ? al : 0.2f * al;
        ex[c] = __expf(al);
    }
    float4* po = (float4*)(exarr + (size_t)pos * 8);
    po[0] = make_float4(ex[0], ex[1], ex[2], ex[3]);
    po[1] = make_float4(ex[4], ex[5], ex[6], ex[7]);
}

// ---------------- small precompute ----------------
// grid 268 x 256
__global__ void k_pre1(const float* fcv_W1, const float* fcv_W2, const float* fcv_b1, const float* fcv_b2,
                       const float* fm_W1, const float* fm_W2, const float* fm_b1, const float* fm_b2,
                       const float* W_cov, const float* as_cov, const float* ad_cov,
                       const float* W_mean, const float* as_mean, const float* ad_mean,
                       float* Wcv, float* Wm, float* bcv2, float* bm2, float* vcov, float* vmean) {
    int b = blockIdx.x, t = threadIdx.x;
    if (b < 256) {  // Wcv[j][c] = sum_k fcv_W1[j][k]*fcv_W2[k][c]; j=b, c=t
        float s = 0.f;
        for (int k = 0; k < 256; ++k) s += fcv_W1[b * 256 + k] * fcv_W2[k * 256 + t];
        Wcv[b * 256 + t] = s;
    } else if (b < 264) {  // vcov[ch][i]: coalesced lanes over j, shuffle-reduce
        int ch = b - 256, h = ch & 3;
        const float* att = (ch < 4) ? as_cov : ad_cov;
        int jl = t & 31, i8 = t >> 5;
        float av[8];
#pragma unroll
        for (int jj = 0; jj < 8; ++jj) av[jj] = att[h * 256 + jj * 32 + jl];
        for (int ii = 0; ii < 32; ++ii) {
            int i = ii * 8 + i8;
            const float* wr = W_cov + (size_t)i * 1024 + h * 256;
            float p = 0.f;
#pragma unroll
            for (int jj = 0; jj < 8; ++jj) p += wr[jj * 32 + jl] * av[jj];
#pragma unroll
            for (int off = 16; off; off >>= 1) p += __shfl_xor(p, off);
            if (jl == 0) vcov[ch * 256 + i] = p;
        }
    } else if (b == 264) {  // Wm[j][c], j=t>>4, c=t&15
        int j = t >> 4, c = t & 15;
        float s = 0.f;
        for (int k = 0; k < 16; ++k) s += fm_W1[j * 16 + k] * fm_W2[k * 16 + c];
        Wm[j * 16 + c] = s;
    } else if (b == 265) {  // vmean[ch][i]
        if (t < 128) {
            int ch = t >> 4, i = t & 15, h = ch & 3;
            const float* att = (ch < 4) ? as_mean : ad_mean;
            float s = 0.f;
            for (int j = 0; j < 16; ++j) s += W_mean[i * 64 + h * 16 + j] * att[h * 16 + j];
            vmean[ch * 16 + i] = s;
        }
    } else if (b == 266) {  // bcv2[c] = fcv_b1 @ fcv_W2 + fcv_b2
        float s = fcv_b2[t];
        for (int k = 0; k < 256; ++k) s += fcv_b1[k] * fcv_W2[k * 256 + t];
        bcv2[t] = s;
    } else {  // bm2
        if (t < 16) {
            float s = fm_b2[t];
            for (int k = 0; k < 16; ++k) s += fm_b1[k] * fm_W2[k * 16 + t];
            bm2[t] = s;
        }
    }
}

// grid 1030 x 256.  WpT rows are chunk-swizzled: 16B chunk C stored at C ^ (col & 7).
__global__ void k_pre2(const float* W_cov, const float* W_mean, const float* bias_cov, const float* bias_mean,
                       const float* Wcv, const float* Wm, const float* bcv2, const float* bm2,
                       unsigned short* WpT, float* Wpm, float* bpc, float* bpm) {
    int b = blockIdx.x, t = threadIdx.x;
    if (b < 1024) {  // block=(q,i), thread=c: scalar W_cov row, coalesced Wcv
        int q = b >> 8, i = b & 255;
        const float* wrow = W_cov + (size_t)i * 1024 + q * 256;  // wave-uniform
        float s = 0.f;
        for (int j = 0; j < 256; ++j) s += wrow[j] * Wcv[j * 256 + t];
        int C = q * 32 + (i >> 3);
        int cs = C ^ (t & 7);
        WpT[(size_t)t * 1024 + cs * 8 + (i & 7)] = f2bf(0.25f * s);
    } else if (b < 1028) {  // Wpm[k][c], k=h*16+i
        int idx = (b - 1024) * 256 + t;
        int k = idx >> 4, c = idx & 15, h = k >> 4, i = k & 15;
        float s = 0.f;
        for (int j = 0; j < 16; ++j) s += W_mean[i * 64 + h * 16 + j] * Wm[j * 16 + c];
        Wpm[k * 16 + c] = 0.25f * s;
    } else if (b == 1028) {  // bpc[c] = bias_cov @ Wcv + bcv2
        float s = bcv2[t];
        for (int j = 0; j < 256; ++j) s += bias_cov[j] * Wcv[j * 256 + t];
        bpc[t] = s;
    } else {
        if (t < 16) {
            float s = bm2[t];
            for (int j = 0; j < 16; ++j) s += bias_mean[j] * Wm[j * 16 + t];
            bpm[t] = s;
        }
    }
}

// ---------------- per-node attention dots + cov->bf16 pack ----------------
// grid 12500 x 256 (wave per node)
__global__ void __launch_bounds__(256) k_dots(const float* cov, const float* mean,
                                              const float* vcov, const float* vmean,
                                              float* asrc, float* adst, unsigned short* covb) {
    __shared__ float vc[8 * 256];
    __shared__ float vm[8 * 16];
    int t = threadIdx.x;
    for (int i = t; i < 2048; i += 256) vc[i] = vcov[i];
    if (t < 128) vm[t] = vmean[t];
    __syncthreads();
    int w = t >> 6, lane = t & 63;
    int n = blockIdx.x * 4 + w;
    float4 x = *(const float4*)(cov + (size_t)n * 256 + lane * 4);
    // pack to bf16
    unsigned int u0 = (unsigned int)f2bf(x.x) | ((unsigned int)f2bf(x.y) << 16);
    unsigned int u1 = (unsigned int)f2bf(x.z) | ((unsigned int)f2bf(x.w) << 16);
    *(uint2*)((char*)covb + (size_t)n * 512 + lane * 8) = make_uint2(u0, u1);
    float p[8];
#pragma unroll
    for (int c = 0; c < 8; ++c) {
        float4 v = *(const float4*)&vc[c * 256 + lane * 4];
        p[c] = x.x * v.x + x.y * v.y + x.z * v.z + x.w * v.w;
    }
#pragma unroll
    for (int c = 0; c < 8; ++c)
        for (int off = 32; off; off >>= 1) p[c] += __shfl_xor(p[c], off);
    float xm = (lane < 16) ? mean[(size_t)n * 16 + lane] : 0.f;
    float q[8];
#pragma unroll
    for (int c = 0; c < 8; ++c) {
        q[c] = (lane < 16) ? xm * vm[c * 16 + lane] : 0.f;
        for (int off = 8; off; off >>= 1) q[c] += __shfl_xor(q[c], off);
    }
    if (lane == 0) {
        float4* ps = (float4*)(asrc + (size_t)n * 8);
        ps[0] = make_float4(p[0], p[1], p[2], p[3]);  // src_cov heads
        ps[1] = make_float4(q[0], q[1], q[2], q[3]);  // src_mean heads
        float4* pd = (float4*)(adst + (size_t)n * 8);
        pd[0] = make_float4(p[4], p[5], p[6], p[7]);  // dst_cov
        pd[1] = make_float4(q[4], q[5], q[6], q[7]);  // dst_mean
    }
}

// ---------------- per-dst softmax denominators (8 channels) ----------------
// 16 lanes per node; CSR-sequential exarr reads. grid 3125 x 256
__global__ void __launch_bounds__(256) k_dsum(const int* row_start, const float* exarr, float* dsum) {
    int t = threadIdx.x;
    int n = blockIdx.x * 16 + (t >> 4);
    int sl = t & 15;
    int beg = row_start[n], deg = row_start[n + 1] - beg;
    f32x4 s0 = (f32x4){0.f, 0.f, 0.f, 0.f}, s1 = s0;
    for (int i = sl; i < deg; i += 16) {
        const f32x4* p = (const f32x4*)(exarr + (size_t)(beg + i) * 8);
        s0 += p[0];
        s1 += p[1];
    }
#pragma unroll
    for (int off = 1; off < 16; off <<= 1) {
#pragma unroll
        for (int e = 0; e < 4; ++e) {
            s0[e] += __shfl_xor(s0[e], off);
            s1[e] += __shfl_xor(s1[e], off);
        }
    }
    if (sl == 0) {
        f32x4* pd = (f32x4*)(dsum + (size_t)n * 8);
        pd[0] = s0;
        pd[1] = s1;
    }
}

// ---------------- edge aggregation: wave per dst node, full wave per edge ----------------
// No LDS, no dsum work, no mean epilogue. Ycat rows chunk-swizzled by (n&7).
// grid 12500 x 256
__global__ void __launch_bounds__(256) k_agg(const int* row_start, const int* srt, const float* exarr,
                                             const unsigned short* covb, const float* mean,
                                             const float* dsum,
                                             unsigned short* Ycat, float* Ym) {
    int t = threadIdx.x;
    int w = t >> 6, lane = t & 63;
    int n = blockIdx.x * 4 + w;
    int beg = row_start[n], deg = row_start[n + 1] - beg;
    const int* sp = srt + beg;
    const float* exb = exarr + (size_t)beg * 8;
    int ml = lane & 15;

    f32x2 acc[8];  // [h*2+g]: head h, cols lane*4 + g*2 + {0,1}
#pragma unroll
    for (int k = 0; k < 8; ++k) acc[k] = (f32x2){0.f, 0.f};
    float accm[4] = {0, 0, 0, 0};

    int j = 0;
    for (; j + 4 <= deg; j += 4) {
        int ss[4];
        float4 e0[4], e1[4];
#pragma unroll
        for (int k = 0; k < 4; ++k) {
            ss[k] = sp[j + k];  // wave-uniform broadcast
            e0[k] = *(const float4*)(exb + (size_t)(j + k) * 8);
            e1[k] = *(const float4*)(exb + (size_t)(j + k) * 8 + 4);
        }
        uint2 cd[4];
        float mv[4];
#pragma unroll
        for (int k = 0; k < 4; ++k) {
            cd[k] = *(const uint2*)((const char*)covb + (size_t)ss[k] * 512 + lane * 8);
            mv[k] = mean[(size_t)ss[k] * 16 + ml];
        }
#pragma unroll
        for (int k = 0; k < 4; ++k) {
            f32x2 x0 = (f32x2){__uint_as_float(cd[k].x << 16), __uint_as_float(cd[k].x & 0xffff0000u)};
            f32x2 x1 = (f32x2){__uint_as_float(cd[k].y << 16), __uint_as_float(cd[k].y & 0xffff0000u)};
            float ev[4] = {e0[k].x, e0[k].y, e0[k].z, e0[k].w};
#pragma unroll
            for (int h = 0; h < 4; ++h) {
                f32x2 e2 = (f32x2){ev[h], ev[h]};
                acc[h * 2 + 0] = __builtin_elementwise_fma(e2, x0, acc[h * 2 + 0]);
                acc[h * 2 + 1] = __builtin_elementwise_fma(e2, x1, acc[h * 2 + 1]);
            }
            accm[0] += e1[k].x * mv[k]; accm[1] += e1[k].y * mv[k];
            accm[2] += e1[k].z * mv[k]; accm[3] += e1[k].w * mv[k];
        }
    }
    for (; j < deg; ++j) {  // tail
        int ss = sp[j];
        float4 e0 = *(const float4*)(exb + (size_t)j * 8);
        float4 e1 = *(const float4*)(exb + (size_t)j * 8 + 4);
        uint2 cd = *(const uint2*)((const char*)covb + (size_t)ss * 512 + lane * 8);
        float mv = mean[(size_t)ss * 16 + ml];
        f32x2 x0 = (f32x2){__uint_as_float(cd.x << 16), __uint_as_float(cd.x & 0xffff0000u)};
        f32x2 x1 = (f32x2){__uint_as_float(cd.y << 16), __uint_as_float(cd.y & 0xffff0000u)};
        float ev[4] = {e0.x, e0.y, e0.z, e0.w};
#pragma unroll
        for (int h = 0; h < 4; ++h) {
            f32x2 e2 = (f32x2){ev[h], ev[h]};
            acc[h * 2 + 0] = __builtin_elementwise_fma(e2, x0, acc[h * 2 + 0]);
            acc[h * 2 + 1] = __builtin_elementwise_fma(e2, x1, acc[h * 2 + 1]);
        }
        accm[0] += e1.x * mv; accm[1] += e1.y * mv;
        accm[2] += e1.z * mv; accm[3] += e1.w * mv;
    }

    const float4* pds = (const float4*)(dsum + (size_t)n * 8);
    float4 d0 = pds[0], d1 = pds[1];
    float invc[4] = {1.f / (d0.x + 1e-16f), 1.f / (d0.y + 1e-16f),
                     1.f / (d0.z + 1e-16f), 1.f / (d0.w + 1e-16f)};
    float invm[4] = {1.f / (d1.x + 1e-16f), 1.f / (d1.y + 1e-16f),
                     1.f / (d1.z + 1e-16f), 1.f / (d1.w + 1e-16f)};
    // Ycat bf16, swizzled: logical chunk C = h*32 + lane/2 stored at C ^ (n&7)
    char* yrow = (char*)Ycat + (size_t)n * 2048;
    int cbase = lane >> 1, hl = lane & 1, sw = n & 7;
#pragma unroll
    for (int h = 0; h < 4; ++h) {
        float iv = invc[h];
        uint2 pk;
        pk.x = (unsigned int)f2bf(acc[h * 2 + 0].x * iv) | ((unsigned int)f2bf(acc[h * 2 + 0].y * iv) << 16);
        pk.y = (unsigned int)f2bf(acc[h * 2 + 1].x * iv) | ((unsigned int)f2bf(acc[h * 2 + 1].y * iv) << 16);
        int cs = (h * 32 + cbase) ^ sw;
        *(uint2*)(yrow + cs * 16 + hl * 8) = pk;
    }
    if (lane < 16) {
#pragma unroll
        for (int h = 0; h < 4; ++h) Ym[(size_t)n * 64 + h * 16 + lane] = accm[h] * invm[h];
    }
}

// ---------------- mean output: out = Ym[N,64] @ Wpm[64,16] + bpm ----------------
// grid 3125 x 256 (16 nodes x 16 cols per block)
__global__ void __launch_bounds__(256) k_meanout(const float* Ym, const float* Wpm, const float* bpm,
                                                 float* out_mean) {
    __shared__ float wm[1024];
    __shared__ float bmv[16];
    int t = threadIdx.x;
    for (int i = t; i < 1024; i += 256) wm[i] = Wpm[i];
    if (t < 16) bmv[t] = bpm[t];
    __syncthreads();
    int node = blockIdx.x * 16 + (t >> 4), c = t & 15;
    const float* yr = Ym + (size_t)node * 64;
    float s = bmv[c];
#pragma unroll
    for (int k = 0; k < 64; ++k) s += yr[k] * wm[k * 16 + c];
    out_mean[(size_t)node * 16 + c] = s;
}

// ---------------- final cov GEMM: [50000,1024]bf16 @ WpT[256][1024]bf16 -> f32 ----------------
// grid 391*2 x 256; 128x128 tile, BK=64, global_load_lds; XOR-swizzled chunks kill bank conflicts
__global__ void __launch_bounds__(256) k_gemm(const unsigned short* Ycat, const unsigned short* WpT,
                                              const float* bpc, float* out_cov) {
    __shared__ __align__(16) unsigned short As[128 * 64];  // 16KB (swizzled image)
    __shared__ __align__(16) unsigned short Bs[128 * 64];  // 16KB (swizzled image)
    int t = threadIdx.x;
    int m0 = (blockIdx.x >> 1) * 128, c0 = (blockIdx.x & 1) * 128;
    int w = t >> 6, lane = t & 63;
    int mg = w >> 1, ng = w & 1;
    int q = lane >> 4, lm = lane & 15;
    f32x4 acc[4][4];
#pragma unroll
    for (int mt = 0; mt < 4; ++mt)
#pragma unroll
        for (int nt = 0; nt < 4; ++nt) acc[mt][nt] = (f32x4){0.f, 0.f, 0.f, 0.f};

    for (int kc = 0; kc < 16; ++kc) {
        int k0 = kc * 64;
#pragma unroll
        for (int i2 = 0; i2 < 4; ++i2) {  // As: 1024 x 16B segments
            int idx = t + i2 * 256;
            int row = idx >> 3, seg = idx & 7;
            int gm = m0 + row;
            if (gm < NN)
                gl2lds16(Ycat + (size_t)gm * 1024 + k0 + seg * 8, As + idx * 8);
        }
#pragma unroll
        for (int i2 = 0; i2 < 4; ++i2) {  // Bs: 1024 x 16B segments
            int idx = t + i2 * 256;
            int col = idx >> 3, seg = idx & 7;
            gl2lds16(WpT + (size_t)(c0 + col) * 1024 + k0 + seg * 8, Bs + idx * 8);
        }
        __syncthreads();
#pragma unroll
        for (int ks = 0; ks < 2; ++ks) {
            bf16x8 af[4], bfr[4];
#pragma unroll
            for (int mt = 0; mt < 4; ++mt) {
                int row = mg * 64 + mt * 16 + lm;
                int ch = (ks * 4 + q) ^ (row & 7);
                af[mt] = *(const bf16x8*)(As + row * 64 + ch * 8);
            }
#pragma unroll
            for (int nt = 0; nt < 4; ++nt) {
                int col = ng * 64 + nt * 16 + lm;
                int ch = (ks * 4 + q) ^ (col & 7);
                bfr[nt] = *(const bf16x8*)(Bs + col * 64 + ch * 8);
            }
#pragma unroll
            for (int mt = 0; mt < 4; ++mt)
#pragma unroll
                for (int nt = 0; nt < 4; ++nt)
                    acc[mt][nt] = __builtin_amdgcn_mfma_f32_16x16x32_bf16(af[mt], bfr[nt], acc[mt][nt], 0, 0, 0);
        }
        __syncthreads();
    }
#pragma unroll
    for (int nt = 0; nt < 4; ++nt) {
        int col = c0 + ng * 64 + nt * 16 + lm;
        float bias = bpc[col];
#pragma unroll
        for (int mt = 0; mt < 4; ++mt) {
#pragma unroll
            for (int e = 0; e < 4; ++e) {
                int r = m0 + mg * 64 + mt * 16 + q * 4 + e;
                if (r < NN)
                    __builtin_nontemporal_store(acc[mt][nt][e] + bias, &out_cov[(size_t)r * 256 + col]);
            }
        }
    }
}

extern "C" void kernel_launch(void* const* d_in, const int* in_sizes, int n_in,
                              void* d_out, int out_size, void* d_ws, size_t ws_size,
                              hipStream_t stream) {
    const float* mean = (const float*)d_in[0];
    const float* cov = (const float*)d_in[1];
    const int* ei = (const int*)d_in[2];
    const float* W_mean = (const float*)d_in[3];
    const float* as_mean = (const float*)d_in[4];
    const float* ad_mean = (const float*)d_in[5];
    const float* bias_mean = (const float*)d_in[6];
    const float* W_cov = (const float*)d_in[7];
    const float* as_cov = (const float*)d_in[8];
    const float* ad_cov = (const float*)d_in[9];
    const float* bias_cov = (const float*)d_in[10];
    const float* fm_W1 = (const float*)d_in[11];
    const float* fm_b1 = (const float*)d_in[12];
    const float* fm_W2 = (const float*)d_in[13];
    const float* fm_b2 = (const float*)d_in[14];
    const float* fcv_W1 = (const float*)d_in[15];
    const float* fcv_b1 = (const float*)d_in[16];
    const float* fcv_W2 = (const float*)d_in[17];
    const float* fcv_b2 = (const float*)d_in[18];

    float* out_mean = (float*)d_out;
    float* out_cov = (float*)d_out + (size_t)NN * DD;

    char* w = (char*)d_ws;
    auto alloc = [&](size_t bytes) -> void* {
        void* p = (void*)w;
        w += (bytes + 255) & ~(size_t)255;
        return p;
    };
    unsigned short* Ycat = (unsigned short*)alloc((size_t)NN * 1024 * 2);
    unsigned short* covb = (unsigned short*)alloc((size_t)NN * 256 * 2);
    float* exarr = (float*)alloc((size_t)ETOT * 8 * 4);
    float* Ym = (float*)alloc((size_t)NN * 64 * 4);
    float* dsum = (float*)alloc((size_t)NN * 8 * 4);
    int* counts = (int*)alloc(NN * 4);
    int* partial = (int*)alloc(NN * 4);
    int* bsum = (int*)alloc(256 * 4);
    int* boff = (int*)alloc(256 * 4);
    int* row_start = (int*)alloc((NN + 1) * 4);
    int* cursor = (int*)alloc(NN * 4);
    int* srt = (int*)alloc((size_t)ETOT * 4);
    float* asrc = (float*)alloc((size_t)NN * 8 * 4);
    float* adst = (float*)alloc((size_t)NN * 8 * 4);
    float* vcov = (float*)alloc(8 * 256 * 4);
    float* vmean = (float*)alloc(8 * 16 * 4);
    float* Wcv = (float*)alloc(256 * 256 * 4);
    float* Wm = (float*)alloc(16 * 16 * 4);
    float* bcv2 = (float*)alloc(256 * 4);
    float* bm2 = (float*)alloc(16 * 4);
    unsigned short* WpT = (unsigned short*)alloc(256 * 1024 * 2);
    float* bpc = (float*)alloc(256 * 4);
    float* Wpm = (float*)alloc(64 * 16 * 4);
    float* bpm = (float*)alloc(16 * 4);

    hipMemsetAsync(counts, 0, NN * 4, stream);
    k_count<<<(EE + 255) / 256, 256, 0, stream>>>(ei, counts);
    k_scan1<<<NB, 256, 0, stream>>>(counts, partial, bsum);
    k_scan2<<<1, 256, 0, stream>>>(bsum, boff);
    k_scan3<<<NB, 256, 0, stream>>>(counts, partial, boff, row_start, cursor);
    k_pre1<<<268, 256, 0, stream>>>(fcv_W1, fcv_W2, fcv_b1, fcv_b2, fm_W1, fm_W2, fm_b1, fm_b2,
                                    W_cov, as_cov, ad_cov, W_mean, as_mean, ad_mean,
                                    Wcv, Wm, bcv2, bm2, vcov, vmean);
    k_pre2<<<1030, 256, 0, stream>>>(W_cov, W_mean, bias_cov, bias_mean, Wcv, Wm, bcv2, bm2,
                                     WpT, Wpm, bpc, bpm);
    k_dots<<<NN / 4, 256, 0, stream>>>(cov, mean, vcov, vmean, asrc, adst, covb);
    k_scatter<<<(ETOT + 255) / 256, 256, 0, stream>>>(ei, cursor, asrc, adst, srt, exarr);
    k_dsum<<<3125, 256, 0, stream>>>(row_start, exarr, dsum);
    k_agg<<<NN / 4, 256, 0, stream>>>(row_start, srt, exarr, covb, mean, dsum, Ycat, Ym);
    k_gemm<<<391 * 2, 256, 0, stream>>>(Ycat, WpT, bpc, out_cov);
    k_meanout<<<3125, 256, 0, stream>>>(Ym, Wpm, bpm, out_mean);
}

// Round 6
// 472.297 us; speedup vs baseline: 1.1042x; 1.1042x over previous
//
#include <hip/hip_runtime.h>

#define NN 50000
#define EE 800000
#define DD 16
#define DD2 256
#define ETOT (EE + NN)
#define NB 196  // ceil(50000/256)

typedef __bf16 bf16x8 __attribute__((ext_vector_type(8)));
typedef float f32x4 __attribute__((ext_vector_type(4)));
typedef float f32x2 __attribute__((ext_vector_type(2)));

__device__ inline unsigned short f2bf(float f) {
    unsigned int u = __float_as_uint(f);
    return (unsigned short)((u + 0x7FFFu + ((u >> 16) & 1u)) >> 16);
}

__device__ inline void gl2lds16(const void* g, void* l) {
    __builtin_amdgcn_global_load_lds((const __attribute__((address_space(1))) unsigned int*)g,
                                     (__attribute__((address_space(3))) unsigned int*)l, 16, 0, 0);
}

// ---------------- CSR build ----------------
__global__ void k_count(const int* ei, int* counts) {
    int e = blockIdx.x * 256 + threadIdx.x;
    if (e < EE) atomicAdd(&counts[ei[EE + e]], 1);
}

__global__ void k_scan1(const int* counts, int* partial, int* bsum) {
    __shared__ int sh[256];
    int t = threadIdx.x;
    int n = blockIdx.x * 256 + t;
    int v = (n < NN) ? counts[n] + 1 : 0;  // +1 self-loop
    sh[t] = v;
    __syncthreads();
    for (int d = 1; d < 256; d <<= 1) {
        int x = (t >= d) ? sh[t - d] : 0;
        __syncthreads();
        sh[t] += x;
        __syncthreads();
    }
    if (n < NN) partial[n] = sh[t];
    if (t == 255) bsum[blockIdx.x] = sh[255];
}

__global__ void k_scan2(const int* bsum, int* boff) {  // 1 block
    __shared__ int sh[256];
    int t = threadIdx.x;
    int v = (t < NB) ? bsum[t] : 0;
    sh[t] = v;
    __syncthreads();
    for (int d = 1; d < 256; d <<= 1) {
        int x = (t >= d) ? sh[t - d] : 0;
        __syncthreads();
        sh[t] += x;
        __syncthreads();
    }
    if (t < NB) boff[t] = sh[t] - v;  // exclusive
}

__global__ void k_scan3(const int* counts, const int* partial, const int* boff,
                        int* row_start, int* cursor) {
    int n = blockIdx.x * 256 + threadIdx.x;
    if (n < NN) {
        int rs = partial[n] - (counts[n] + 1) + boff[blockIdx.x];
        row_start[n] = rs;
        cursor[n] = rs;
        if (n == NN - 1) row_start[NN] = partial[n] + boff[blockIdx.x];
    }
}

// minimal scatter: only srt
__global__ void k_scatter(const int* ei, int* cursor, int* srt) {
    int i = blockIdx.x * 256 + threadIdx.x;
    if (i >= ETOT) return;
    int s, d;
    if (i < EE) { s = ei[i]; d = ei[EE + i]; }
    else { s = d = i - EE; }
    int pos = atomicAdd(&cursor[d], 1);
    srt[pos] = s;
}

// ---------------- fused precompute: WpT, bpc, vcov, vmean, Wpm, bpm ----------------
// grid 1034 x 256
__global__ void k_pre(const float* fcv_W1, const float* fcv_W2, const float* fcv_b1, const float* fcv_b2,
                      const float* fm_W1, const float* fm_W2, const float* fm_b1, const float* fm_b2,
                      const float* W_cov, const float* as_cov, const float* ad_cov,
                      const float* W_mean, const float* as_mean, const float* ad_mean,
                      const float* bias_cov, const float* bias_mean,
                      unsigned short* WpT, float* bpc, float* vcov, float* vmean,
                      float* Wpm, float* bpm) {
    __shared__ float sh[256];
    int b = blockIdx.x, t = threadIdx.x;
    if (b < 1024) {
        // WpT[c][q*256+i] = 0.25 * (W_cov_row(i,q) @ fcv_W1 @ fcv_W2)[c], chunk-swizzled
        int q = b >> 8, i = b & 255;
        const float* wrow = W_cov + (size_t)i * 1024 + q * 256;  // wave-uniform
        float t1 = 0.f;
        for (int j = 0; j < 256; ++j) t1 += wrow[j] * fcv_W1[j * 256 + t];
        sh[t] = t1;
        __syncthreads();
        float s = 0.f;
        for (int k = 0; k < 256; ++k) s += sh[k] * fcv_W2[k * 256 + t];
        int C = q * 32 + (i >> 3);
        int cs = C ^ (t & 7);
        WpT[(size_t)t * 1024 + cs * 8 + (i & 7)] = f2bf(0.25f * s);
    } else if (b == 1024) {
        // bpc = (bias_cov @ fcv_W1 + fcv_b1) @ fcv_W2 + fcv_b2
        float t1 = fcv_b1[t];
        for (int j = 0; j < 256; ++j) t1 += bias_cov[j] * fcv_W1[j * 256 + t];
        sh[t] = t1;
        __syncthreads();
        float s = fcv_b2[t];
        for (int k = 0; k < 256; ++k) s += sh[k] * fcv_W2[k * 256 + t];
        bpc[t] = s;
    } else if (b < 1033) {
        // vcov[ch][i]: coalesced lanes over j, shuffle-reduce
        int ch = b - 1025, h = ch & 3;
        const float* att = (ch < 4) ? as_cov : ad_cov;
        int jl = t & 31, i8 = t >> 5;
        float av[8];
#pragma unroll
        for (int jj = 0; jj < 8; ++jj) av[jj] = att[h * 256 + jj * 32 + jl];
        for (int ii = 0; ii < 32; ++ii) {
            int i = ii * 8 + i8;
            const float* wr = W_cov + (size_t)i * 1024 + h * 256;
            float p = 0.f;
#pragma unroll
            for (int jj = 0; jj < 8; ++jj) p += wr[jj * 32 + jl] * av[jj];
#pragma unroll
            for (int off = 16; off; off >>= 1) p += __shfl_xor(p, off);
            if (jl == 0) vcov[ch * 256 + i] = p;
        }
    } else {
        // mean-side: Wm (LDS), vmean, Wpm, bpm
        {
            int j = t >> 4, c = t & 15;
            float s = 0.f;
            for (int k = 0; k < 16; ++k) s += fm_W1[j * 16 + k] * fm_W2[k * 16 + c];
            sh[j * 16 + c] = s;
        }
        if (t < 128) {
            int ch = t >> 4, i = t & 15, h = ch & 3;
            const float* att = (ch < 4) ? as_mean : ad_mean;
            float s = 0.f;
            for (int j = 0; j < 16; ++j) s += W_mean[i * 64 + h * 16 + j] * att[h * 16 + j];
            vmean[ch * 16 + i] = s;
        }
        __syncthreads();
#pragma unroll
        for (int r = 0; r < 4; ++r) {
            int idx = r * 256 + t;
            int k = idx >> 4, c = idx & 15, h = k >> 4, i = k & 15;
            float s = 0.f;
            for (int j = 0; j < 16; ++j) s += W_mean[i * 64 + h * 16 + j] * sh[j * 16 + c];
            Wpm[k * 16 + c] = 0.25f * s;
        }
        if (t < 16) {
            float b2 = fm_b2[t];
            for (int k = 0; k < 16; ++k) b2 += fm_b1[k] * fm_W2[k * 16 + t];
            float s = b2;
            for (int j = 0; j < 16; ++j) s += bias_mean[j] * sh[j * 16 + t];
            bpm[t] = s;
        }
    }
}

// ---------------- per-node attention dots + cov->bf16 pack ----------------
// grid 12500 x 256 (wave per node)
__global__ void __launch_bounds__(256) k_dots(const float* cov, const float* mean,
                                              const float* vcov, const float* vmean,
                                              float* asrc, float* adst, unsigned short* covb) {
    __shared__ float vc[8 * 256];
    __shared__ float vm[8 * 16];
    int t = threadIdx.x;
    for (int i = t; i < 2048; i += 256) vc[i] = vcov[i];
    if (t < 128) vm[t] = vmean[t];
    __syncthreads();
    int w = t >> 6, lane = t & 63;
    int n = blockIdx.x * 4 + w;
    float4 x = *(const float4*)(cov + (size_t)n * 256 + lane * 4);
    unsigned int u0 = (unsigned int)f2bf(x.x) | ((unsigned int)f2bf(x.y) << 16);
    unsigned int u1 = (unsigned int)f2bf(x.z) | ((unsigned int)f2bf(x.w) << 16);
    *(uint2*)((char*)covb + (size_t)n * 512 + lane * 8) = make_uint2(u0, u1);
    float p[8];
#pragma unroll
    for (int c = 0; c < 8; ++c) {
        float4 v = *(const float4*)&vc[c * 256 + lane * 4];
        p[c] = x.x * v.x + x.y * v.y + x.z * v.z + x.w * v.w;
    }
#pragma unroll
    for (int c = 0; c < 8; ++c)
        for (int off = 32; off; off >>= 1) p[c] += __shfl_xor(p[c], off);
    float xm = (lane < 16) ? mean[(size_t)n * 16 + lane] : 0.f;
    float q[8];
#pragma unroll
    for (int c = 0; c < 8; ++c) {
        q[c] = (lane < 16) ? xm * vm[c * 16 + lane] : 0.f;
        for (int off = 8; off; off >>= 1) q[c] += __shfl_xor(q[c], off);
    }
    if (lane == 0) {
        float4* ps = (float4*)(asrc + (size_t)n * 8);
        ps[0] = make_float4(p[0], p[1], p[2], p[3]);
        ps[1] = make_float4(q[0], q[1], q[2], q[3]);
        float4* pd = (float4*)(adst + (size_t)n * 8);
        pd[0] = make_float4(p[4], p[5], p[6], p[7]);
        pd[1] = make_float4(q[4], q[5], q[6], q[7]);
    }
}

// ---------------- per-edge exp coefficients + per-dst denominators ----------------
// 16 lanes per node; sequential srt reads, sequential exarr writes. grid 3125 x 256
__global__ void __launch_bounds__(256) k_coefdsum(const int* row_start, const int* srt,
                                                  const float* asrc, const float* adst,
                                                  float* exarr, float* dsum) {
    int t = threadIdx.x;
    int n = blockIdx.x * 16 + (t >> 4);
    int sl = t & 15;
    int beg = row_start[n], deg = row_start[n + 1] - beg;
    const float4* pd = (const float4*)(adst + (size_t)n * 8);
    float4 d0 = pd[0], d1 = pd[1];
    float dv[8] = {d0.x, d0.y, d0.z, d0.w, d1.x, d1.y, d1.z, d1.w};
    f32x4 s0 = (f32x4){0.f, 0.f, 0.f, 0.f}, s1 = s0;
    for (int i = sl; i < deg; i += 16) {
        int s = srt[beg + i];
        const float4* pa = (const float4*)(asrc + (size_t)s * 8);
        float4 a0 = pa[0], a1 = pa[1];
        float av[8] = {a0.x, a0.y, a0.z, a0.w, a1.x, a1.y, a1.z, a1.w};
        float ex[8];
#pragma unroll
        for (int c = 0; c < 8; ++c) {
            float al = av[c] + dv[c];
            al = (al >= 0.f) ? al : 0.2f * al;
            ex[c] = __expf(al);
        }
        s0 += (f32x4){ex[0], ex[1], ex[2], ex[3]};
        s1 += (f32x4){ex[4], ex[5], ex[6], ex[7]};
        float4* po = (float4*)(exarr + (size_t)(beg + i) * 8);
        po[0] = make_float4(ex[0], ex[1], ex[2], ex[3]);
        po[1] = make_float4(ex[4], ex[5], ex[6], ex[7]);
    }
#pragma unroll
    for (int off = 1; off < 16; off <<= 1) {
#pragma unroll
        for (int e = 0; e < 4; ++e) {
            s0[e] += __shfl_xor(s0[e], off);
            s1[e] += __shfl_xor(s1[e], off);
        }
    }
    if (sl == 0) {
        f32x4* pds = (f32x4*)(dsum + (size_t)n * 8);
        pds[0] = s0;
        pds[1] = s1;
    }
}

// ---------------- edge aggregation: wave per dst node, full wave per edge ----------------
// srt values prefetched one group ahead to break the srt->gather chain.
// grid 12500 x 256
__global__ void __launch_bounds__(256) k_agg(const int* row_start, const int* srt, const float* exarr,
                                             const unsigned short* covb, const float* mean,
                                             const float* dsum,
                                             unsigned short* Ycat, float* Ym) {
    int t = threadIdx.x;
    int w = t >> 6, lane = t & 63;
    int n = blockIdx.x * 4 + w;
    int beg = row_start[n], deg = row_start[n + 1] - beg;
    const int* sp = srt + beg;
    const float* exb = exarr + (size_t)beg * 8;
    int ml = lane & 15;

    f32x2 acc[8];
#pragma unroll
    for (int k = 0; k < 8; ++k) acc[k] = (f32x2){0.f, 0.f};
    float accm[4] = {0, 0, 0, 0};

    int G = deg >> 2;
    int ss[4];
    if (G > 0) {
#pragma unroll
        for (int k = 0; k < 4; ++k) ss[k] = sp[k];
    }
    for (int g = 0; g < G; ++g) {
        int j = g << 2;
        float4 e0[4], e1[4];
#pragma unroll
        for (int k = 0; k < 4; ++k) {
            e0[k] = *(const float4*)(exb + (size_t)(j + k) * 8);
            e1[k] = *(const float4*)(exb + (size_t)(j + k) * 8 + 4);
        }
        uint2 cd[4];
        float mv[4];
#pragma unroll
        for (int k = 0; k < 4; ++k) {
            cd[k] = *(const uint2*)((const char*)covb + (size_t)ss[k] * 512 + lane * 8);
            mv[k] = mean[(size_t)ss[k] * 16 + ml];
        }
        int ns[4];
#pragma unroll
        for (int k = 0; k < 4; ++k) ns[k] = ss[k];
        if (g + 1 < G) {
#pragma unroll
            for (int k = 0; k < 4; ++k) ns[k] = sp[j + 4 + k];
        }
#pragma unroll
        for (int k = 0; k < 4; ++k) {
            f32x2 x0 = (f32x2){__uint_as_float(cd[k].x << 16), __uint_as_float(cd[k].x & 0xffff0000u)};
            f32x2 x1 = (f32x2){__uint_as_float(cd[k].y << 16), __uint_as_float(cd[k].y & 0xffff0000u)};
            float ev[4] = {e0[k].x, e0[k].y, e0[k].z, e0[k].w};
#pragma unroll
            for (int h = 0; h < 4; ++h) {
                f32x2 e2 = (f32x2){ev[h], ev[h]};
                acc[h * 2 + 0] = __builtin_elementwise_fma(e2, x0, acc[h * 2 + 0]);
                acc[h * 2 + 1] = __builtin_elementwise_fma(e2, x1, acc[h * 2 + 1]);
            }
            accm[0] += e1[k].x * mv[k]; accm[1] += e1[k].y * mv[k];
            accm[2] += e1[k].z * mv[k]; accm[3] += e1[k].w * mv[k];
        }
#pragma unroll
        for (int k = 0; k < 4; ++k) ss[k] = ns[k];
    }
    for (int j = G << 2; j < deg; ++j) {  // tail
        int sv = sp[j];
        float4 e0 = *(const float4*)(exb + (size_t)j * 8);
        float4 e1 = *(const float4*)(exb + (size_t)j * 8 + 4);
        uint2 cd = *(const uint2*)((const char*)covb + (size_t)sv * 512 + lane * 8);
        float mv = mean[(size_t)sv * 16 + ml];
        f32x2 x0 = (f32x2){__uint_as_float(cd.x << 16), __uint_as_float(cd.x & 0xffff0000u)};
        f32x2 x1 = (f32x2){__uint_as_float(cd.y << 16), __uint_as_float(cd.y & 0xffff0000u)};
        float ev[4] = {e0.x, e0.y, e0.z, e0.w};
#pragma unroll
        for (int h = 0; h < 4; ++h) {
            f32x2 e2 = (f32x2){ev[h], ev[h]};
            acc[h * 2 + 0] = __builtin_elementwise_fma(e2, x0, acc[h * 2 + 0]);
            acc[h * 2 + 1] = __builtin_elementwise_fma(e2, x1, acc[h * 2 + 1]);
        }
        accm[0] += e1.x * mv; accm[1] += e1.y * mv;
        accm[2] += e1.z * mv; accm[3] += e1.w * mv;
    }

    const float4* pds = (const float4*)(dsum + (size_t)n * 8);
    float4 d0 = pds[0], d1 = pds[1];
    float invc[4] = {1.f / (d0.x + 1e-16f), 1.f / (d0.y + 1e-16f),
                     1.f / (d0.z + 1e-16f), 1.f / (d0.w + 1e-16f)};
    float invm[4] = {1.f / (d1.x + 1e-16f), 1.f / (d1.y + 1e-16f),
                     1.f / (d1.z + 1e-16f), 1.f / (d1.w + 1e-16f)};
    // Ycat bf16, swizzled: logical chunk C = h*32 + lane/2 stored at C ^ (n&7)
    char* yrow = (char*)Ycat + (size_t)n * 2048;
    int cbase = lane >> 1, hl = lane & 1, sw = n & 7;
#pragma unroll
    for (int h = 0; h < 4; ++h) {
        float iv = invc[h];
        uint2 pk;
        pk.x = (unsigned int)f2bf(acc[h * 2 + 0].x * iv) | ((unsigned int)f2bf(acc[h * 2 + 0].y * iv) << 16);
        pk.y = (unsigned int)f2bf(acc[h * 2 + 1].x * iv) | ((unsigned int)f2bf(acc[h * 2 + 1].y * iv) << 16);
        int cs = (h * 32 + cbase) ^ sw;
        *(uint2*)(yrow + cs * 16 + hl * 8) = pk;
    }
    if (lane < 16) {
#pragma unroll
        for (int h = 0; h < 4; ++h) Ym[(size_t)n * 64 + h * 16 + lane] = accm[h] * invm[h];
    }
}

// ---------------- final cov GEMM + fused mean output ----------------
// blocks [0,782): 128x128 GEMM tiles; blocks [782,1564): mean output (64 nodes each)
__global__ void __launch_bounds__(256) k_gemm(const unsigned short* Ycat, const unsigned short* WpT,
                                              const float* bpc, float* out_cov,
                                              const float* Ym, const float* Wpm, const float* bpm,
                                              float* out_mean) {
    __shared__ __align__(16) unsigned short As[128 * 64];  // 16KB (swizzled image)
    __shared__ __align__(16) unsigned short Bs[128 * 64];  // 16KB (swizzled image)
    int t = threadIdx.x;
    if (blockIdx.x >= 782) {
        // mean output: out = Ym[N,64] @ Wpm[64,16] + bpm
        float* wm = (float*)As;
        float* bmv = (float*)Bs;
        for (int i = t; i < 1024; i += 256) wm[i] = Wpm[i];
        if (t < 16) bmv[t] = bpm[t];
        __syncthreads();
        int base = (blockIdx.x - 782) * 64;
        int c = t & 15;
#pragma unroll
        for (int p = 0; p < 4; ++p) {
            int node = base + p * 16 + (t >> 4);
            if (node < NN) {
                const float* yr = Ym + (size_t)node * 64;
                float s = bmv[c];
#pragma unroll
                for (int k = 0; k < 64; ++k) s += yr[k] * wm[k * 16 + c];
                out_mean[(size_t)node * 16 + c] = s;
            }
        }
        return;
    }
    int m0 = (blockIdx.x >> 1) * 128, c0 = (blockIdx.x & 1) * 128;
    int w = t >> 6, lane = t & 63;
    int mg = w >> 1, ng = w & 1;
    int q = lane >> 4, lm = lane & 15;
    f32x4 acc[4][4];
#pragma unroll
    for (int mt = 0; mt < 4; ++mt)
#pragma unroll
        for (int nt = 0; nt < 4; ++nt) acc[mt][nt] = (f32x4){0.f, 0.f, 0.f, 0.f};

    for (int kc = 0; kc < 16; ++kc) {
        int k0 = kc * 64;
#pragma unroll
        for (int i2 = 0; i2 < 4; ++i2) {
            int idx = t + i2 * 256;
            int row = idx >> 3, seg = idx & 7;
            int gm = m0 + row;
            if (gm < NN)
                gl2lds16(Ycat + (size_t)gm * 1024 + k0 + seg * 8, As + idx * 8);
        }
#pragma unroll
        for (int i2 = 0; i2 < 4; ++i2) {
            int idx = t + i2 * 256;
            int col = idx >> 3, seg = idx & 7;
            gl2lds16(WpT + (size_t)(c0 + col) * 1024 + k0 + seg * 8, Bs + idx * 8);
        }
        __syncthreads();
#pragma unroll
        for (int ks = 0; ks < 2; ++ks) {
            bf16x8 af[4], bfr[4];
#pragma unroll
            for (int mt = 0; mt < 4; ++mt) {
                int row = mg * 64 + mt * 16 + lm;
                int ch = (ks * 4 + q) ^ (row & 7);
                af[mt] = *(const bf16x8*)(As + row * 64 + ch * 8);
            }
#pragma unroll
            for (int nt = 0; nt < 4; ++nt) {
                int col = ng * 64 + nt * 16 + lm;
                int ch = (ks * 4 + q) ^ (col & 7);
                bfr[nt] = *(const bf16x8*)(Bs + col * 64 + ch * 8);
            }
#pragma unroll
            for (int mt = 0; mt < 4; ++mt)
#pragma unroll
                for (int nt = 0; nt < 4; ++nt)
                    acc[mt][nt] = __builtin_amdgcn_mfma_f32_16x16x32_bf16(af[mt], bfr[nt], acc[mt][nt], 0, 0, 0);
        }
        __syncthreads();
    }
#pragma unroll
    for (int nt = 0; nt < 4; ++nt) {
        int col = c0 + ng * 64 + nt * 16 + lm;
        float bias = bpc[col];
#pragma unroll
        for (int mt = 0; mt < 4; ++mt) {
#pragma unroll
            for (int e = 0; e < 4; ++e) {
                int r = m0 + mg * 64 + mt * 16 + q * 4 + e;
                if (r < NN)
                    __builtin_nontemporal_store(acc[mt][nt][e] + bias, &out_cov[(size_t)r * 256 + col]);
            }
        }
    }
}

extern "C" void kernel_launch(void* const* d_in, const int* in_sizes, int n_in,
                              void* d_out, int out_size, void* d_ws, size_t ws_size,
                              hipStream_t stream) {
    const float* mean = (const float*)d_in[0];
    const float* cov = (const float*)d_in[1];
    const int* ei = (const int*)d_in[2];
    const float* W_mean = (const float*)d_in[3];
    const float* as_mean = (const float*)d_in[4];
    const float* ad_mean = (const float*)d_in[5];
    const float* bias_mean = (const float*)d_in[6];
    const float* W_cov = (const float*)d_in[7];
    const float* as_cov = (const float*)d_in[8];
    const float* ad_cov = (const float*)d_in[9];
    const float* bias_cov = (const float*)d_in[10];
    const float* fm_W1 = (const float*)d_in[11];
    const float* fm_b1 = (const float*)d_in[12];
    const float* fm_W2 = (const float*)d_in[13];
    const float* fm_b2 = (const float*)d_in[14];
    const float* fcv_W1 = (const float*)d_in[15];
    const float* fcv_b1 = (const float*)d_in[16];
    const float* fcv_W2 = (const float*)d_in[17];
    const float* fcv_b2 = (const float*)d_in[18];

    float* out_mean = (float*)d_out;
    float* out_cov = (float*)d_out + (size_t)NN * DD;

    char* w = (char*)d_ws;
    auto alloc = [&](size_t bytes) -> void* {
        void* p = (void*)w;
        w += (bytes + 255) & ~(size_t)255;
        return p;
    };
    unsigned short* Ycat = (unsigned short*)alloc((size_t)NN * 1024 * 2);
    unsigned short* covb = (unsigned short*)alloc((size_t)NN * 256 * 2);
    float* exarr = (float*)alloc((size_t)ETOT * 8 * 4);
    float* Ym = (float*)alloc((size_t)NN * 64 * 4);
    float* dsum = (float*)alloc((size_t)NN * 8 * 4);
    int* counts = (int*)alloc(NN * 4);
    int* partial = (int*)alloc(NN * 4);
    int* bsum = (int*)alloc(256 * 4);
    int* boff = (int*)alloc(256 * 4);
    int* row_start = (int*)alloc((NN + 1) * 4);
    int* cursor = (int*)alloc(NN * 4);
    int* srt = (int*)alloc((size_t)ETOT * 4);
    float* asrc = (float*)alloc((size_t)NN * 8 * 4);
    float* adst = (float*)alloc((size_t)NN * 8 * 4);
    float* vcov = (float*)alloc(8 * 256 * 4);
    float* vmean = (float*)alloc(8 * 16 * 4);
    unsigned short* WpT = (unsigned short*)alloc(256 * 1024 * 2);
    float* bpc = (float*)alloc(256 * 4);
    float* Wpm = (float*)alloc(64 * 16 * 4);
    float* bpm = (float*)alloc(16 * 4);

    hipMemsetAsync(counts, 0, NN * 4, stream);
    k_count<<<(EE + 255) / 256, 256, 0, stream>>>(ei, counts);
    k_scan1<<<NB, 256, 0, stream>>>(counts, partial, bsum);
    k_scan2<<<1, 256, 0, stream>>>(bsum, boff);
    k_scan3<<<NB, 256, 0, stream>>>(counts, partial, boff, row_start, cursor);
    k_scatter<<<(ETOT + 255) / 256, 256, 0, stream>>>(ei, cursor, srt);
    k_pre<<<1034, 256, 0, stream>>>(fcv_W1, fcv_W2, fcv_b1, fcv_b2, fm_W1, fm_W2, fm_b1, fm_b2,
                                    W_cov, as_cov, ad_cov, W_mean, as_mean, ad_mean,
                                    bias_cov, bias_mean, WpT, bpc, vcov, vmean, Wpm, bpm);
    k_dots<<<NN / 4, 256, 0, stream>>>(cov, mean, vcov, vmean, asrc, adst, covb);
    k_coefdsum<<<3125, 256, 0, stream>>>(row_start, srt, asrc, adst, exarr, dsum);
    k_agg<<<NN / 4, 256, 0, stream>>>(row_start, srt, exarr, covb, mean, dsum, Ycat, Ym);
    k_gemm<<<782 + 782, 256, 0, stream>>>(Ycat, WpT, bpc, out_cov, Ym, Wpm, bpm, out_mean);
}

// Round 7
// 464.499 us; speedup vs baseline: 1.1228x; 1.0168x over previous
//
#include <hip/hip_runtime.h>

#define NN 50000
#define EE 800000
#define DD 16
#define DD2 256
#define ETOT (EE + NN)
#define NB 196  // ceil(50000/256)

typedef __bf16 bf16x8 __attribute__((ext_vector_type(8)));
typedef float f32x4 __attribute__((ext_vector_type(4)));
typedef float f32x2 __attribute__((ext_vector_type(2)));

__device__ inline unsigned short f2bf(float f) {
    unsigned int u = __float_as_uint(f);
    return (unsigned short)((u + 0x7FFFu + ((u >> 16) & 1u)) >> 16);
}

__device__ inline void gl2lds16(const void* g, void* l) {
    __builtin_amdgcn_global_load_lds((const __attribute__((address_space(1))) unsigned int*)g,
                                     (__attribute__((address_space(3))) unsigned int*)l, 16, 0, 0);
}

// ---------------- CSR build ----------------
__global__ void k_count(const int* ei, int* counts) {
    int e = blockIdx.x * 256 + threadIdx.x;
    if (e < EE) atomicAdd(&counts[ei[EE + e]], 1);
}

__global__ void k_scan1(const int* counts, int* partial, int* bsum) {
    __shared__ int sh[256];
    int t = threadIdx.x;
    int n = blockIdx.x * 256 + t;
    int v = (n < NN) ? counts[n] + 1 : 0;  // +1 self-loop
    sh[t] = v;
    __syncthreads();
    for (int d = 1; d < 256; d <<= 1) {
        int x = (t >= d) ? sh[t - d] : 0;
        __syncthreads();
        sh[t] += x;
        __syncthreads();
    }
    if (n < NN) partial[n] = sh[t];
    if (t == 255) bsum[blockIdx.x] = sh[255];
}

// merged scan2+scan3: every block redundantly scans bsum[0..NB)
__global__ void k_scan3(const int* counts, const int* partial, const int* bsum,
                        int* row_start, int* cursor) {
    __shared__ int sh[256];
    int t = threadIdx.x;
    int v = (t < NB) ? bsum[t] : 0;
    sh[t] = v;
    __syncthreads();
    for (int d = 1; d < 256; d <<= 1) {
        int x = (t >= d) ? sh[t - d] : 0;
        __syncthreads();
        sh[t] += x;
        __syncthreads();
    }
    int boff = (blockIdx.x == 0) ? 0 : sh[blockIdx.x - 1];
    int n = blockIdx.x * 256 + t;
    if (n < NN) {
        int rs = partial[n] - (counts[n] + 1) + boff;
        row_start[n] = rs;
        cursor[n] = rs;
        if (n == NN - 1) row_start[NN] = partial[n] + boff;
    }
}

// minimal scatter: only srt
__global__ void k_scatter(const int* ei, int* cursor, int* srt) {
    int i = blockIdx.x * 256 + threadIdx.x;
    if (i >= ETOT) return;
    int s, d;
    if (i < EE) { s = ei[i]; d = ei[EE + i]; }
    else { s = d = i - EE; }
    int pos = atomicAdd(&cursor[d], 1);
    srt[pos] = s;
}

// ---------------- fused precompute: WpT, bpc, vcov, vmean, Wpm, bpm ----------------
// grid 1034 x 256
__global__ void k_pre(const float* fcv_W1, const float* fcv_W2, const float* fcv_b1, const float* fcv_b2,
                      const float* fm_W1, const float* fm_W2, const float* fm_b1, const float* fm_b2,
                      const float* W_cov, const float* as_cov, const float* ad_cov,
                      const float* W_mean, const float* as_mean, const float* ad_mean,
                      const float* bias_cov, const float* bias_mean,
                      unsigned short* WpT, float* bpc, float* vcov, float* vmean,
                      float* Wpm, float* bpm) {
    __shared__ float sh[256];
    int b = blockIdx.x, t = threadIdx.x;
    if (b < 1024) {
        // WpT[c][q*256+i] = 0.25 * (W_cov_row(i,q) @ fcv_W1 @ fcv_W2)[c], chunk-swizzled
        int q = b >> 8, i = b & 255;
        const float* wrow = W_cov + (size_t)i * 1024 + q * 256;  // wave-uniform
        float t1 = 0.f;
        for (int j = 0; j < 256; ++j) t1 += wrow[j] * fcv_W1[j * 256 + t];
        sh[t] = t1;
        __syncthreads();
        float s = 0.f;
        for (int k = 0; k < 256; ++k) s += sh[k] * fcv_W2[k * 256 + t];
        int C = q * 32 + (i >> 3);
        int cs = C ^ (t & 7);
        WpT[(size_t)t * 1024 + cs * 8 + (i & 7)] = f2bf(0.25f * s);
    } else if (b == 1024) {
        // bpc = (bias_cov @ fcv_W1 + fcv_b1) @ fcv_W2 + fcv_b2
        float t1 = fcv_b1[t];
        for (int j = 0; j < 256; ++j) t1 += bias_cov[j] * fcv_W1[j * 256 + t];
        sh[t] = t1;
        __syncthreads();
        float s = fcv_b2[t];
        for (int k = 0; k < 256; ++k) s += sh[k] * fcv_W2[k * 256 + t];
        bpc[t] = s;
    } else if (b < 1033) {
        // vcov[ch][i]: coalesced lanes over j, shuffle-reduce
        int ch = b - 1025, h = ch & 3;
        const float* att = (ch < 4) ? as_cov : ad_cov;
        int jl = t & 31, i8 = t >> 5;
        float av[8];
#pragma unroll
        for (int jj = 0; jj < 8; ++jj) av[jj] = att[h * 256 + jj * 32 + jl];
        for (int ii = 0; ii < 32; ++ii) {
            int i = ii * 8 + i8;
            const float* wr = W_cov + (size_t)i * 1024 + h * 256;
            float p = 0.f;
#pragma unroll
            for (int jj = 0; jj < 8; ++jj) p += wr[jj * 32 + jl] * av[jj];
#pragma unroll
            for (int off = 16; off; off >>= 1) p += __shfl_xor(p, off);
            if (jl == 0) vcov[ch * 256 + i] = p;
        }
    } else {
        // mean-side: Wm (LDS), vmean, Wpm, bpm
        {
            int j = t >> 4, c = t & 15;
            float s = 0.f;
            for (int k = 0; k < 16; ++k) s += fm_W1[j * 16 + k] * fm_W2[k * 16 + c];
            sh[j * 16 + c] = s;
        }
        if (t < 128) {
            int ch = t >> 4, i = t & 15, h = ch & 3;
            const float* att = (ch < 4) ? as_mean : ad_mean;
            float s = 0.f;
            for (int j = 0; j < 16; ++j) s += W_mean[i * 64 + h * 16 + j] * att[h * 16 + j];
            vmean[ch * 16 + i] = s;
        }
        __syncthreads();
#pragma unroll
        for (int r = 0; r < 4; ++r) {
            int idx = r * 256 + t;
            int k = idx >> 4, c = idx & 15, h = k >> 4, i = k & 15;
            float s = 0.f;
            for (int j = 0; j < 16; ++j) s += W_mean[i * 64 + h * 16 + j] * sh[j * 16 + c];
            Wpm[k * 16 + c] = 0.25f * s;
        }
        if (t < 16) {
            float b2 = fm_b2[t];
            for (int k = 0; k < 16; ++k) b2 += fm_b1[k] * fm_W2[k * 16 + t];
            float s = b2;
            for (int j = 0; j < 16; ++j) s += bias_mean[j] * sh[j * 16 + t];
            bpm[t] = s;
        }
    }
}

// ---------------- per-node attention dots + cov->bf16 pack ----------------
// grid 12500 x 256 (wave per node)
__global__ void __launch_bounds__(256) k_dots(const float* cov, const float* mean,
                                              const float* vcov, const float* vmean,
                                              float* asrc, float* adst, unsigned short* covb) {
    __shared__ float vc[8 * 256];
    __shared__ float vm[8 * 16];
    int t = threadIdx.x;
    for (int i = t; i < 2048; i += 256) vc[i] = vcov[i];
    if (t < 128) vm[t] = vmean[t];
    __syncthreads();
    int w = t >> 6, lane = t & 63;
    int n = blockIdx.x * 4 + w;
    float4 x = *(const float4*)(cov + (size_t)n * 256 + lane * 4);
    unsigned int u0 = (unsigned int)f2bf(x.x) | ((unsigned int)f2bf(x.y) << 16);
    unsigned int u1 = (unsigned int)f2bf(x.z) | ((unsigned int)f2bf(x.w) << 16);
    *(uint2*)((char*)covb + (size_t)n * 512 + lane * 8) = make_uint2(u0, u1);
    float p[8];
#pragma unroll
    for (int c = 0; c < 8; ++c) {
        float4 v = *(const float4*)&vc[c * 256 + lane * 4];
        p[c] = x.x * v.x + x.y * v.y + x.z * v.z + x.w * v.w;
    }
#pragma unroll
    for (int c = 0; c < 8; ++c)
        for (int off = 32; off; off >>= 1) p[c] += __shfl_xor(p[c], off);
    float xm = (lane < 16) ? mean[(size_t)n * 16 + lane] : 0.f;
    float q[8];
#pragma unroll
    for (int c = 0; c < 8; ++c) {
        q[c] = (lane < 16) ? xm * vm[c * 16 + lane] : 0.f;
        for (int off = 8; off; off >>= 1) q[c] += __shfl_xor(q[c], off);
    }
    if (lane == 0) {
        float4* ps = (float4*)(asrc + (size_t)n * 8);
        ps[0] = make_float4(p[0], p[1], p[2], p[3]);
        ps[1] = make_float4(q[0], q[1], q[2], q[3]);
        float4* pd = (float4*)(adst + (size_t)n * 8);
        pd[0] = make_float4(p[4], p[5], p[6], p[7]);
        pd[1] = make_float4(q[4], q[5], q[6], q[7]);
    }
}

// ---------------- edge aggregation: wave per dst node ----------------
// Per 64-edge chunk: lane e computes exp (per-lane, efficient) + stages to wave-private LDS;
// aggregation loop broadcasts se via __shfl and ex via uniform ds_read. Softmax denominator
// accumulated per-lane, shuffle-reduced at the end (no separate pass / kernels).
// grid 12500 x 256
__global__ void __launch_bounds__(256) k_agg(const int* row_start, const int* srt,
                                             const float* asrc, const float* adst,
                                             const unsigned short* covb, const float* mean,
                                             unsigned short* Ycat, float* Ym) {
    __shared__ float exbuf[4][64][8];
    int t = threadIdx.x;
    int w = t >> 6, lane = t & 63;
    int n = blockIdx.x * 4 + w;
    int beg = row_start[n], deg = row_start[n + 1] - beg;
    int ml = lane & 15;
    float ad[8];
    {
        const float4* pd = (const float4*)(adst + (size_t)n * 8);
        float4 d0 = pd[0], d1 = pd[1];
        ad[0] = d0.x; ad[1] = d0.y; ad[2] = d0.z; ad[3] = d0.w;
        ad[4] = d1.x; ad[5] = d1.y; ad[6] = d1.z; ad[7] = d1.w;
    }
    f32x2 acc[8];
#pragma unroll
    for (int k = 0; k < 8; ++k) acc[k] = (f32x2){0.f, 0.f};
    float accm[4] = {0, 0, 0, 0};
    float ds8[8] = {0, 0, 0, 0, 0, 0, 0, 0};

    for (int base = 0; base < deg; base += 64) {
        int i = base + lane;
        bool valid = i < deg;
        int s0 = srt[beg + (valid ? i : (deg - 1))];  // clamped: dup rows coalesce
        const float4* pa = (const float4*)(asrc + (size_t)s0 * 8);
        float4 a0 = pa[0], a1 = pa[1];
        float av[8] = {a0.x, a0.y, a0.z, a0.w, a1.x, a1.y, a1.z, a1.w};
        float ex8[8];
#pragma unroll
        for (int c = 0; c < 8; ++c) {
            float al = av[c] + ad[c];
            al = (al >= 0.f) ? al : 0.2f * al;
            float e = __expf(al);
            e = valid ? e : 0.f;
            ex8[c] = e;
            ds8[c] += e;
        }
        *(float4*)&exbuf[w][lane][0] = make_float4(ex8[0], ex8[1], ex8[2], ex8[3]);
        *(float4*)&exbuf[w][lane][4] = make_float4(ex8[4], ex8[5], ex8[6], ex8[7]);
        // wave-private LDS region: same-wave RAW handled by compiler lgkmcnt
        int cnt = min(64, deg - base);
        int cnt4 = (cnt + 3) & ~3;  // padding edges have ex=0, clamped se
        for (int jp = 0; jp < cnt4; jp += 4) {
            int se[4];
            float4 e0[4], e1[4];
#pragma unroll
            for (int k = 0; k < 4; ++k) se[k] = __shfl(s0, jp + k);
#pragma unroll
            for (int k = 0; k < 4; ++k) {
                e0[k] = *(const float4*)&exbuf[w][jp + k][0];
                e1[k] = *(const float4*)&exbuf[w][jp + k][4];
            }
            uint2 cd[4];
            float mv[4];
#pragma unroll
            for (int k = 0; k < 4; ++k) {
                cd[k] = *(const uint2*)((const char*)covb + (size_t)se[k] * 512 + lane * 8);
                mv[k] = mean[(size_t)se[k] * 16 + ml];
            }
#pragma unroll
            for (int k = 0; k < 4; ++k) {
                f32x2 x0 = (f32x2){__uint_as_float(cd[k].x << 16), __uint_as_float(cd[k].x & 0xffff0000u)};
                f32x2 x1 = (f32x2){__uint_as_float(cd[k].y << 16), __uint_as_float(cd[k].y & 0xffff0000u)};
                float ev[4] = {e0[k].x, e0[k].y, e0[k].z, e0[k].w};
#pragma unroll
                for (int h = 0; h < 4; ++h) {
                    f32x2 e2 = (f32x2){ev[h], ev[h]};
                    acc[h * 2 + 0] = __builtin_elementwise_fma(e2, x0, acc[h * 2 + 0]);
                    acc[h * 2 + 1] = __builtin_elementwise_fma(e2, x1, acc[h * 2 + 1]);
                }
                accm[0] += e1[k].x * mv[k]; accm[1] += e1[k].y * mv[k];
                accm[2] += e1[k].z * mv[k]; accm[3] += e1[k].w * mv[k];
            }
        }
    }
#pragma unroll
    for (int c = 0; c < 8; ++c)
        for (int off = 32; off; off >>= 1) ds8[c] += __shfl_xor(ds8[c], off);

    float invc[4] = {1.f / (ds8[0] + 1e-16f), 1.f / (ds8[1] + 1e-16f),
                     1.f / (ds8[2] + 1e-16f), 1.f / (ds8[3] + 1e-16f)};
    float invm[4] = {1.f / (ds8[4] + 1e-16f), 1.f / (ds8[5] + 1e-16f),
                     1.f / (ds8[6] + 1e-16f), 1.f / (ds8[7] + 1e-16f)};
    // Ycat bf16, swizzled: logical chunk C = h*32 + lane/2 stored at C ^ (n&7)
    char* yrow = (char*)Ycat + (size_t)n * 2048;
    int cbase = lane >> 1, hl = lane & 1, sw = n & 7;
#pragma unroll
    for (int h = 0; h < 4; ++h) {
        float iv = invc[h];
        uint2 pk;
        pk.x = (unsigned int)f2bf(acc[h * 2 + 0].x * iv) | ((unsigned int)f2bf(acc[h * 2 + 0].y * iv) << 16);
        pk.y = (unsigned int)f2bf(acc[h * 2 + 1].x * iv) | ((unsigned int)f2bf(acc[h * 2 + 1].y * iv) << 16);
        int cs = (h * 32 + cbase) ^ sw;
        *(uint2*)(yrow + cs * 16 + hl * 8) = pk;
    }
    if (lane < 16) {
#pragma unroll
        for (int h = 0; h < 4; ++h) Ym[(size_t)n * 64 + h * 16 + lane] = accm[h] * invm[h];
    }
}

// ---------------- final cov GEMM + fused mean output ----------------
// blocks [0,782): 128x128 GEMM tiles; blocks [782,978): mean output (256 nodes each)
__global__ void __launch_bounds__(256) k_gemm(const unsigned short* Ycat, const unsigned short* WpT,
                                              const float* bpc, float* out_cov,
                                              const float* Ym, const float* Wpm, const float* bpm,
                                              float* out_mean) {
    __shared__ __align__(16) unsigned short As[128 * 64];  // 16KB (swizzled image)
    __shared__ __align__(16) unsigned short Bs[128 * 64];  // 16KB (swizzled image)
    int t = threadIdx.x;
    if (blockIdx.x >= 782) {
        // mean output: out = Ym[N,64] @ Wpm[64,16] + bpm
        float* wm = (float*)As;
        float* bmv = (float*)Bs;
        for (int i = t; i < 1024; i += 256) wm[i] = Wpm[i];
        if (t < 16) bmv[t] = bpm[t];
        __syncthreads();
        int base = (blockIdx.x - 782) * 256;
        int c = t & 15;
#pragma unroll
        for (int p = 0; p < 16; ++p) {
            int node = base + p * 16 + (t >> 4);
            if (node < NN) {
                const float* yr = Ym + (size_t)node * 64;
                float s = bmv[c];
#pragma unroll
                for (int k = 0; k < 64; ++k) s += yr[k] * wm[k * 16 + c];
                out_mean[(size_t)node * 16 + c] = s;
            }
        }
        return;
    }
    int m0 = (blockIdx.x >> 1) * 128, c0 = (blockIdx.x & 1) * 128;
    int w = t >> 6, lane = t & 63;
    int mg = w >> 1, ng = w & 1;
    int q = lane >> 4, lm = lane & 15;
    f32x4 acc[4][4];
#pragma unroll
    for (int mt = 0; mt < 4; ++mt)
#pragma unroll
        for (int nt = 0; nt < 4; ++nt) acc[mt][nt] = (f32x4){0.f, 0.f, 0.f, 0.f};

    for (int kc = 0; kc < 16; ++kc) {
        int k0 = kc * 64;
#pragma unroll
        for (int i2 = 0; i2 < 4; ++i2) {
            int idx = t + i2 * 256;
            int row = idx >> 3, seg = idx & 7;
            int gm = m0 + row;
            if (gm < NN)
                gl2lds16(Ycat + (size_t)gm * 1024 + k0 + seg * 8, As + idx * 8);
        }
#pragma unroll
        for (int i2 = 0; i2 < 4; ++i2) {
            int idx = t + i2 * 256;
            int col = idx >> 3, seg = idx & 7;
            gl2lds16(WpT + (size_t)(c0 + col) * 1024 + k0 + seg * 8, Bs + idx * 8);
        }
        __syncthreads();
#pragma unroll
        for (int ks = 0; ks < 2; ++ks) {
            bf16x8 af[4], bfr[4];
#pragma unroll
            for (int mt = 0; mt < 4; ++mt) {
                int row = mg * 64 + mt * 16 + lm;
                int ch = (ks * 4 + q) ^ (row & 7);
                af[mt] = *(const bf16x8*)(As + row * 64 + ch * 8);
            }
#pragma unroll
            for (int nt = 0; nt < 4; ++nt) {
                int col = ng * 64 + nt * 16 + lm;
                int ch = (ks * 4 + q) ^ (col & 7);
                bfr[nt] = *(const bf16x8*)(Bs + col * 64 + ch * 8);
            }
#pragma unroll
            for (int mt = 0; mt < 4; ++mt)
#pragma unroll
                for (int nt = 0; nt < 4; ++nt)
                    acc[mt][nt] = __builtin_amdgcn_mfma_f32_16x16x32_bf16(af[mt], bfr[nt], acc[mt][nt], 0, 0, 0);
        }
        __syncthreads();
    }
#pragma unroll
    for (int nt = 0; nt < 4; ++nt) {
        int col = c0 + ng * 64 + nt * 16 + lm;
        float bias = bpc[col];
#pragma unroll
        for (int mt = 0; mt < 4; ++mt) {
#pragma unroll
            for (int e = 0; e < 4; ++e) {
                int r = m0 + mg * 64 + mt * 16 + q * 4 + e;
                if (r < NN)
                    __builtin_nontemporal_store(acc[mt][nt][e] + bias, &out_cov[(size_t)r * 256 + col]);
            }
        }
    }
}

extern "C" void kernel_launch(void* const* d_in, const int* in_sizes, int n_in,
                              void* d_out, int out_size, void* d_ws, size_t ws_size,
                              hipStream_t stream) {
    const float* mean = (const float*)d_in[0];
    const float* cov = (const float*)d_in[1];
    const int* ei = (const int*)d_in[2];
    const float* W_mean = (const float*)d_in[3];
    const float* as_mean = (const float*)d_in[4];
    const float* ad_mean = (const float*)d_in[5];
    const float* bias_mean = (const float*)d_in[6];
    const float* W_cov = (const float*)d_in[7];
    const float* as_cov = (const float*)d_in[8];
    const float* ad_cov = (const float*)d_in[9];
    const float* bias_cov = (const float*)d_in[10];
    const float* fm_W1 = (const float*)d_in[11];
    const float* fm_b1 = (const float*)d_in[12];
    const float* fm_W2 = (const float*)d_in[13];
    const float* fm_b2 = (const float*)d_in[14];
    const float* fcv_W1 = (const float*)d_in[15];
    const float* fcv_b1 = (const float*)d_in[16];
    const float* fcv_W2 = (const float*)d_in[17];
    const float* fcv_b2 = (const float*)d_in[18];

    float* out_mean = (float*)d_out;
    float* out_cov = (float*)d_out + (size_t)NN * DD;

    char* w = (char*)d_ws;
    auto alloc = [&](size_t bytes) -> void* {
        void* p = (void*)w;
        w += (bytes + 255) & ~(size_t)255;
        return p;
    };
    unsigned short* Ycat = (unsigned short*)alloc((size_t)NN * 1024 * 2);
    unsigned short* covb = (unsigned short*)alloc((size_t)NN * 256 * 2);
    float* Ym = (float*)alloc((size_t)NN * 64 * 4);
    int* counts = (int*)alloc(NN * 4);
    int* partial = (int*)alloc(NN * 4);
    int* bsum = (int*)alloc(256 * 4);
    int* row_start = (int*)alloc((NN + 1) * 4);
    int* cursor = (int*)alloc(NN * 4);
    int* srt = (int*)alloc((size_t)ETOT * 4);
    float* asrc = (float*)alloc((size_t)NN * 8 * 4);
    float* adst = (float*)alloc((size_t)NN * 8 * 4);
    float* vcov = (float*)alloc(8 * 256 * 4);
    float* vmean = (float*)alloc(8 * 16 * 4);
    unsigned short* WpT = (unsigned short*)alloc(256 * 1024 * 2);
    float* bpc = (float*)alloc(256 * 4);
    float* Wpm = (float*)alloc(64 * 16 * 4);
    float* bpm = (float*)alloc(16 * 4);

    hipMemsetAsync(counts, 0, NN * 4, stream);
    k_count<<<(EE + 255) / 256, 256, 0, stream>>>(ei, counts);
    k_scan1<<<NB, 256, 0, stream>>>(counts, partial, bsum);
    k_scan3<<<NB, 256, 0, stream>>>(counts, partial, bsum, row_start, cursor);
    k_scatter<<<(ETOT + 255) / 256, 256, 0, stream>>>(ei, cursor, srt);
    k_pre<<<1034, 256, 0, stream>>>(fcv_W1, fcv_W2, fcv_b1, fcv_b2, fm_W1, fm_W2, fm_b1, fm_b2,
                                    W_cov, as_cov, ad_cov, W_mean, as_mean, ad_mean,
                                    bias_cov, bias_mean, WpT, bpc, vcov, vmean, Wpm, bpm);
    k_dots<<<NN / 4, 256, 0, stream>>>(cov, mean, vcov, vmean, asrc, adst, covb);
    k_agg<<<NN / 4, 256, 0, stream>>>(row_start, srt, asrc, adst, covb, mean, Ycat, Ym);
    k_gemm<<<782 + 196, 256, 0, stream>>>(Ycat, WpT, bpc, out_cov, Ym, Wpm, bpm, out_mean);
}